// Round 11
// baseline (608.278 us; speedup 1.0000x reference)
//
#include <hip/hip_runtime.h>
#include <math.h>

typedef short bf16x8 __attribute__((ext_vector_type(8)));
typedef float f32x16 __attribute__((ext_vector_type(16)));
typedef float f32x4v __attribute__((ext_vector_type(4)));
typedef unsigned short u16;
typedef unsigned int u32;

__device__ __forceinline__ u16 f2bf(float x) {
    u32 u = __float_as_uint(x);
    u += 0x7FFFu + ((u >> 16) & 1u);
    return (u16)(u >> 16);
}

__device__ __forceinline__ u32 cvt_pk_bf16(float lo, float hi) {
    u32 r;
    asm("v_cvt_pk_bf16_f32 %0, %1, %2" : "=v"(r) : "v"(lo), "v"(hi));
    return r;
}

__device__ __forceinline__ void pl32_swap(u32 &x, u32 &y) {
    asm volatile("v_permlane32_swap_b32 %0, %1" : "+v"(x), "+v"(y));
}

__device__ __forceinline__ bf16x8 frag_from(u32 a, u32 b, u32 c, u32 d) {
    union { u32 u[4]; bf16x8 v; } t;
    t.u[0] = a; t.u[1] = b; t.u[2] = c; t.u[3] = d;
    return t.v;
}

// ---------------- weight prepack (same layout as rounds 6-10) ----------------
__global__ void prepack_kernel(const float* __restrict__ Ws1, const float* __restrict__ bs1,
                               const float* __restrict__ Ws2, const float* __restrict__ Wr1,
                               const float* __restrict__ br1, const float* __restrict__ Wr2,
                               u16* __restrict__ ws)
{
    int idx = blockIdx.x * blockDim.x + threadIdx.x;
    if (idx >= 36864) return;
    int e = idx & 511, l = e >> 3, j = e & 7, hi = l >> 5, l31 = l & 31;
    float val = 0.0f;
    if (idx < 12288) {
        int blk = idx >> 9;
        if (blk < 18) {              // rot GEMM1
            int nt = blk / 3, kstep = blk % 3;
            int h = nt * 32 + l31;
            int k = kstep * 16 + 8 * hi + j;
            if (k < 32) {
                int t = k & 3, kk = k >> 2;
                int r_old = (t >> 1) * 16 + 2 * kk + (t & 1);
                val = Wr1[r_old * 192 + h];
            } else if (k == 32) val = br1[h];
        } else {                     // scalar GEMM1 (X cols 32..39 only)
            int h = (blk - 18) * 32 + l31;
            int k = 32 + 8 * hi + j;
            val = (k == 32) ? bs1[h] : ((k >= 33 && k <= 36) ? Ws1[(k - 33) * 192 + h] : 0.0f);
        }
    } else {
        int t = idx - 12288;
        int blk = t >> 9;
        int mlp = blk / 24, rem = blk % 24, ks = rem >> 1, nto = rem & 1;
        int k = 16 * ks + 8 * hi + j;
        int col = nto * 32 + l31;
        val = (mlp == 0 ? Wr2 : Ws2)[k * 64 + col];
    }
    ws[idx] = f2bf(val);
}

// ---------------- main fused kernel: persistent waves, 1 wave = 32-node tiles ----------------
// r10 structure (200->147us: single gload_lds rot_theta fetch, LDS-rotation, NT stores)
// + cross-tile software pipeline: while tile t runs mlp1 (never touches Rs), issue
// tile t+1's rot_theta gload_lds + scalar loads. Exactly-resident grid (<=1024 blocks).
__global__ __launch_bounds__(256, 4) void node_embed_mfma(
    const float* __restrict__ v, const float* __restrict__ force,
    const int* __restrict__ is_moving, const float* __restrict__ rot_theta,
    const float* __restrict__ br2, const float* __restrict__ bs2,
    const u16* __restrict__ wpack,
    float* __restrict__ out, int n, int nTiles)
{
    // per-wave union buffer (2560 B): phase 1 = Xs (32 x 40 u16),
    // phase 2 = Os (8 rows x 72 f32). per-wave Rs: 32 rows x 128 B, XOR-swizzled.
    __shared__ alignas(16)  u16   Buf[4][1280];
    __shared__ alignas(128) float Rs[4][1024];

    const int lane = threadIdx.x & 63;
    const int w    = threadIdx.x >> 6;
    const int hi   = lane >> 5;
    const int l31  = lane & 31;

    const int gw         = blockIdx.x * 4 + w;   // global wave id (uniform per wave)
    const int tileStride = gridDim.x * 4;
    if (gw >= nTiles) return;

    u16*   Xs  = &Buf[w][0];
    float* Os  = reinterpret_cast<float*>(&Buf[w][0]);
    const char* RsB = reinterpret_cast<const char*>(&Rs[w][0]);

    const u16* A1 = wpack;
    const u16* W2 = wpack + 12288;

    const int rowl = lane >> 4;   // epilogue: row within 4-row store group
    const int qd   = lane & 15;   // epilogue: float4 chunk within 64-col row

    // hoisted output biases (tile-invariant)
    const float b2r_a = br2[l31], b2r_b = br2[32 + l31];
    const float b2s_a = bs2[l31], b2s_b = bs2[32 + l31];

    // swizzled source inner-offset for the cooperative fetch (involution with read XOR)
    const u32 inner = ((u32)(lane & 7) * 16u) ^ ((u32)(lane >> 3) << 4);
    const char* gbase = reinterpret_cast<const char*>(rot_theta);

    // issue tile t's rot_theta into Rs (4 x 1KB contiguous, linear LDS dest)
    auto issue_rs = [&](int t) {
        #pragma unroll
        for (int i = 0; i < 4; ++i) {
            int node_i = min(t * 32 + i * 8 + (lane >> 3), n - 1);
            const void* src = gbase + (size_t)node_i * 128 + inner;
            __builtin_amdgcn_global_load_lds(
                (const __attribute__((address_space(1))) u32*)src,
                (__attribute__((address_space(3))) u32*)(&Rs[w][i * 256]),
                16, 0, 0);
        }
    };

    // ---- prologue: issue loads for first tile ----
    int tile = gw;
    issue_rs(tile);
    int   ldn = min(tile * 32 + l31, n - 1);
    float2 p2 = *reinterpret_cast<const float2*>((hi ? v : force) + (size_t)ldn * 2);
    int   mov = is_moving[ldn];

    while (true) {
        const int waveBase = tile * 32;

        // drain prefetch (also compiler memory fence ordering Buf reuse across tiles)
        asm volatile("s_waitcnt vmcnt(0)" ::: "memory");

        // ---- featurization: 2 lanes per node (hi=0 -> force, hi=1 -> v) ----
        const float nrm = sqrtf(p2.x * p2.x + p2.y * p2.y);
        const float c = p2.x / nrm, s = p2.y / nrm;

        u16* xrow = Xs + l31 * 40;
        {
            float pc = c, ps = s;
            const u32 rowswz = (u32)(l31 & 7) << 4;
            #pragma unroll
            for (int k = 0; k < 8; ++k) {
                const u32 off = ((u32)(l31 * 128 + k * 16)) ^ rowswz;
                const float4 R = *reinterpret_cast<const float4*>(RsB + off);
                const float e0 = fmaf(R.x, pc, R.y * ps);
                const float e1 = fmaf(R.z, pc, R.w * ps);
                *reinterpret_cast<u32*>(xrow + 4 * k + 2 * hi) = cvt_pk_bf16(e0, e1);
                const float npc = pc * c - ps * s;
                ps = fmaf(ps, c, pc * s);
                pc = npc;
            }
        }
        // extras: cols 32..39 = [1.0, fn, vn, oh0, oh1, 0, 0, 0]
        {
            const u16 nb = f2bf(nrm);
            u32 pk1, pk2;
            if (hi == 0) { pk1 = 0x3F80u | ((u32)nb << 16);                 // (1.0, fn)
                           pk2 = (mov == 1) ? 0x3F80u : 0u; }               // (oh1, 0)
            else         { pk1 = (u32)nb | ((mov == 0) ? 0x3F800000u : 0u); // (vn, oh0)
                           pk2 = 0u; }
            *reinterpret_cast<u32*>(xrow + 32 + 2 * hi) = pk1;
            *reinterpret_cast<u32*>(xrow + 36 + 2 * hi) = pk2;
        }

        // ---- consume Xs into fragment registers (Xs dead afterwards) ----
        const bf16x8 xb0 = *reinterpret_cast<const bf16x8*>(&Xs[l31 * 40 + 8 * hi]);
        const bf16x8 xb1 = *reinterpret_cast<const bf16x8*>(&Xs[l31 * 40 + 16 + 8 * hi]);
        const bf16x8 xq4 = *reinterpret_cast<const bf16x8*>(&Xs[l31 * 40 + 32]);

        const int nextTile = tile + tileStride;
        const bool hasNext = nextTile < nTiles;
        float2 p2n; int movn = 0;

        #pragma unroll
        for (int mlp = 0; mlp < 2; ++mlp) {
            const float b2a = mlp ? b2s_a : b2r_a;
            const float b2b = mlp ? b2s_b : b2r_b;

            f32x16 acc0, acc1;
            #pragma unroll
            for (int r = 0; r < 16; ++r) { acc0[r] = b2a; acc1[r] = b2b; }

            #pragma unroll
            for (int a = 0; a < 6; ++a) {
                f32x16 d1;
                #pragma unroll
                for (int r = 0; r < 16; ++r) d1[r] = 0.0f;
                if (mlp == 0) {
                    d1 = __builtin_amdgcn_mfma_f32_32x32x16_bf16(
                        *reinterpret_cast<const bf16x8*>(&A1[(a*3+0)*512 + lane*8]), xb0, d1, 0, 0, 0);
                    d1 = __builtin_amdgcn_mfma_f32_32x32x16_bf16(
                        *reinterpret_cast<const bf16x8*>(&A1[(a*3+1)*512 + lane*8]), xb1, d1, 0, 0, 0);
                    d1 = __builtin_amdgcn_mfma_f32_32x32x16_bf16(
                        *reinterpret_cast<const bf16x8*>(&A1[(a*3+2)*512 + lane*8]), xq4, d1, 0, 0, 0);
                } else {
                    d1 = __builtin_amdgcn_mfma_f32_32x32x16_bf16(
                        *reinterpret_cast<const bf16x8*>(&A1[(18+a)*512 + lane*8]), xq4, d1, 0, 0, 0);
                }

                u32 q[8];
                #pragma unroll
                for (int m = 0; m < 8; ++m)
                    q[m] = cvt_pk_bf16(fmaxf(d1[2*m], 0.0f), fmaxf(d1[2*m+1], 0.0f));

                #pragma unroll
                for (int b = 0; b < 2; ++b) {
                    u32 p0 = q[4*b + 0], p2_ = q[4*b + 2];
                    u32 p1 = q[4*b + 1], p3 = q[4*b + 3];
                    pl32_swap(p0, p2_);
                    pl32_swap(p1, p3);
                    const bf16x8 af = frag_from(p0, p1, p2_, p3);
                    const int ks = 2*a + b;
                    acc0 = __builtin_amdgcn_mfma_f32_32x32x16_bf16(
                        af, *reinterpret_cast<const bf16x8*>(&W2[(mlp*24 + ks*2 + 0)*512 + lane*8]),
                        acc0, 0, 0, 0);
                    acc1 = __builtin_amdgcn_mfma_f32_32x32x16_bf16(
                        af, *reinterpret_cast<const bf16x8*>(&W2[(mlp*24 + ks*2 + 1)*512 + lane*8]),
                        acc1, 0, 0, 0);
                }
            }

            // ---- epilogue: stage 8 rows x 64 cols, rotate from Rs (mlp0), NT stores ----
            #pragma unroll
            for (int rq = 0; rq < 4; ++rq) {
                #pragma unroll
                for (int rr = 0; rr < 4; ++rr) {
                    const int r = rq * 4 + rr;
                    Os[(rr + 4*hi) * 72 + l31]      = acc0[r];
                    Os[(rr + 4*hi) * 72 + 32 + l31] = acc1[r];
                }
                #pragma unroll
                for (int g = 0; g < 2; ++g) {
                    const int row   = g * 4 + rowl;                  // 0..7
                    const int srow  = rq * 8 + row;                  // 0..31 (Rs row)
                    const int node0 = waveBase + srow;
                    float4 o = *reinterpret_cast<const float4*>(&Os[row * 72 + 4 * qd]);
                    if (mlp == 0) {
                        const u32 roff = ((u32)(srow * 128 + (qd & 3) * 32))
                                       ^ ((u32)(srow & 7) << 4);
                        const float4 Ra = *reinterpret_cast<const float4*>(RsB + roff);
                        const float4 Rc = *reinterpret_cast<const float4*>(RsB + (roff ^ 16u));
                        {
                            const float a0 = o.x, b0 = o.y;
                            o.x = fmaf(a0, Ra.x, b0 * Ra.z); o.y = fmaf(a0, Ra.y, b0 * Ra.w);
                        }
                        {
                            const float a0 = o.z, b0 = o.w;
                            o.z = fmaf(a0, Rc.x, b0 * Rc.z); o.w = fmaf(a0, Rc.y, b0 * Rc.w);
                        }
                    }
                    if (node0 < n) {
                        float* dst = out + (mlp ? (size_t)0 : (size_t)n * 64)
                                         + (size_t)node0 * 64 + 4 * qd;
                        f32x4v ov;
                        ov[0] = o.x; ov[1] = o.y; ov[2] = o.z; ov[3] = o.w;
                        __builtin_nontemporal_store(ov, reinterpret_cast<f32x4v*>(dst));
                    }
                }
            }

            // ---- after mlp0 (last Rs use): issue next tile's loads; they land during mlp1 ----
            if (mlp == 0 && hasNext) {
                issue_rs(nextTile);
                const int ldn2 = min(nextTile * 32 + l31, n - 1);
                p2n  = *reinterpret_cast<const float2*>((hi ? v : force) + (size_t)ldn2 * 2);
                movn = is_moving[ldn2];
            }
        }

        if (!hasNext) break;
        tile = nextTile;
        p2   = p2n;
        mov  = movn;
    }
}

// ---------------- fallback (VALU) if ws too small ----------------
__global__ __launch_bounds__(256) void node_embed_valu(
    const float* __restrict__ v, const float* __restrict__ force,
    const int* __restrict__ is_moving, const float* __restrict__ rot_theta,
    const float* __restrict__ Ws1, const float* __restrict__ bs1,
    const float* __restrict__ Ws2, const float* __restrict__ bs2,
    const float* __restrict__ Wr1, const float* __restrict__ br1,
    const float* __restrict__ Wr2, const float* __restrict__ br2,
    float* __restrict__ out, int n)
{
    const int node = blockIdx.x * blockDim.x + threadIdx.x;
    if (node >= n) return;
    const float2 f2 = *reinterpret_cast<const float2*>(force + (size_t)node * 2);
    const float2 v2 = *reinterpret_cast<const float2*>(v     + (size_t)node * 2);
    const float fn = sqrtf(f2.x * f2.x + f2.y * f2.y);
    const float vn = sqrtf(v2.x * v2.x + v2.y * v2.y);
    const float cf = f2.x / fn, sf = f2.y / fn;
    const float cv = v2.x / vn, sv = v2.y / vn;
    const int mov = is_moving[node];
    float rotf[16], rotv[16];
    rotf[0] = cf; rotf[1] = sf; rotv[0] = cv; rotv[1] = sv;
    #pragma unroll
    for (int k = 1; k < 8; ++k) {
        rotf[2*k]   = rotf[2*k-2] * cf - rotf[2*k-1] * sf;
        rotf[2*k+1] = rotf[2*k-1] * cf + rotf[2*k-2] * sf;
        rotv[2*k]   = rotv[2*k-2] * cv - rotv[2*k-1] * sv;
        rotv[2*k+1] = rotv[2*k-1] * cv + rotv[2*k-2] * sv;
    }
    const float* Rb = rot_theta + (size_t)node * 32;
    float x_in[32];
    #pragma unroll
    for (int k = 0; k < 8; ++k) {
        const float4 R = *reinterpret_cast<const float4*>(Rb + k * 4);
        { const float a = rotf[2*k], b = rotf[2*k+1];
          x_in[2*k] = fmaf(R.x,a,R.y*b); x_in[2*k+1] = fmaf(R.z,a,R.w*b); }
        { const float a = rotv[2*k], b = rotv[2*k+1];
          x_in[16+2*k] = fmaf(R.x,a,R.y*b); x_in[16+2*k+1] = fmaf(R.z,a,R.w*b); }
    }
    float acc[64];
    #pragma unroll
    for (int j = 0; j < 64; ++j) acc[j] = br2[j];
    for (int h = 0; h < 192; h += 4) {
        float hid[4];
        #pragma unroll
        for (int u = 0; u < 4; ++u) {
            float t = br1[h+u];
            #pragma unroll
            for (int i = 0; i < 32; ++i) t = fmaf(x_in[i], Wr1[i*192+h+u], t);
            hid[u] = fmaxf(t, 0.0f);
        }
        #pragma unroll
        for (int j = 0; j < 64; ++j) {
            float t = acc[j];
            #pragma unroll
            for (int u = 0; u < 4; ++u) t = fmaf(hid[u], Wr2[(h+u)*64+j], t);
            acc[j] = t;
        }
    }
    #pragma unroll
    for (int k = 0; k < 8; ++k) {
        const float4 R = *reinterpret_cast<const float4*>(Rb + k * 4);
        #pragma unroll
        for (int j = 0; j < 4; ++j) {
            const int p = j*16 + 2*k;
            const float a = acc[p], b = acc[p+1];
            acc[p] = fmaf(a,R.x,b*R.z); acc[p+1] = fmaf(a,R.y,b*R.w);
        }
    }
    float* orow = out + (size_t)n * 64 + (size_t)node * 64;
    #pragma unroll
    for (int j = 0; j < 16; ++j)
        *reinterpret_cast<float4*>(orow + 4*j) =
            make_float4(acc[4*j], acc[4*j+1], acc[4*j+2], acc[4*j+3]);
    const float s0 = fn, s1 = vn, s2 = (mov==0)?1.f:0.f, s3 = (mov==1)?1.f:0.f;
    #pragma unroll
    for (int j = 0; j < 64; ++j) acc[j] = bs2[j];
    for (int h = 0; h < 192; h += 4) {
        float hid[4];
        #pragma unroll
        for (int u = 0; u < 4; ++u) {
            float t = bs1[h+u];
            t = fmaf(s0, Ws1[0*192+h+u], t); t = fmaf(s1, Ws1[1*192+h+u], t);
            t = fmaf(s2, Ws1[2*192+h+u], t); t = fmaf(s3, Ws1[3*192+h+u], t);
            hid[u] = fmaxf(t, 0.0f);
        }
        #pragma unroll
        for (int j = 0; j < 64; ++j) {
            float t = acc[j];
            #pragma unroll
            for (int u = 0; u < 4; ++u) t = fmaf(hid[u], Ws2[(h+u)*64+j], t);
            acc[j] = t;
        }
    }
    orow = out + (size_t)node * 64;
    #pragma unroll
    for (int j = 0; j < 16; ++j)
        *reinterpret_cast<float4*>(orow + 4*j) =
            make_float4(acc[4*j], acc[4*j+1], acc[4*j+2], acc[4*j+3]);
}

extern "C" void kernel_launch(void* const* d_in, const int* in_sizes, int n_in,
                              void* d_out, int out_size, void* d_ws, size_t ws_size,
                              hipStream_t stream) {
    const int n = in_sizes[0] / 2;
    if (ws_size >= 36864 * sizeof(u16)) {
        hipLaunchKernelGGL(prepack_kernel, dim3(144), dim3(256), 0, stream,
                           (const float*)d_in[4],   // Ws1
                           (const float*)d_in[5],   // bs1
                           (const float*)d_in[6],   // Ws2
                           (const float*)d_in[8],   // Wr1
                           (const float*)d_in[9],   // br1
                           (const float*)d_in[10],  // Wr2
                           (u16*)d_ws);
        const int nTiles = (n + 31) / 32;
        int blocks = (nTiles + 3) / 4;
        if (blocks > 1024) blocks = 1024;   // exactly-resident: 4 blocks/CU x 256 CU
        hipLaunchKernelGGL(node_embed_mfma, dim3(blocks), dim3(256), 0, stream,
                           (const float*)d_in[0], (const float*)d_in[1],
                           (const int*)d_in[2],   (const float*)d_in[3],
                           (const float*)d_in[11],  // br2
                           (const float*)d_in[7],   // bs2
                           (const u16*)d_ws, (float*)d_out, n, nTiles);
    } else {
        hipLaunchKernelGGL(node_embed_valu, dim3((n + 255) / 256), dim3(256), 0, stream,
                           (const float*)d_in[0], (const float*)d_in[1],
                           (const int*)d_in[2],   (const float*)d_in[3],
                           (const float*)d_in[4], (const float*)d_in[5],
                           (const float*)d_in[6], (const float*)d_in[7],
                           (const float*)d_in[8], (const float*)d_in[9],
                           (const float*)d_in[10],(const float*)d_in[11],
                           (float*)d_out, n);
    }
}

// Round 12
// 146.625 us; speedup vs baseline: 4.1485x; 4.1485x over previous
//
#include <hip/hip_runtime.h>
#include <math.h>

typedef short bf16x8 __attribute__((ext_vector_type(8)));
typedef float f32x16 __attribute__((ext_vector_type(16)));
typedef float f32x4v __attribute__((ext_vector_type(4)));
typedef unsigned short u16;
typedef unsigned int u32;

__device__ __forceinline__ u16 f2bf(float x) {
    u32 u = __float_as_uint(x);
    u += 0x7FFFu + ((u >> 16) & 1u);
    return (u16)(u >> 16);
}

__device__ __forceinline__ u32 cvt_pk_bf16(float lo, float hi) {
    u32 r;
    asm("v_cvt_pk_bf16_f32 %0, %1, %2" : "=v"(r) : "v"(lo), "v"(hi));
    return r;
}

__device__ __forceinline__ void pl32_swap(u32 &x, u32 &y) {
    asm volatile("v_permlane32_swap_b32 %0, %1" : "+v"(x), "+v"(y));
}

__device__ __forceinline__ bf16x8 frag_from(u32 a, u32 b, u32 c, u32 d) {
    union { u32 u[4]; bf16x8 v; } t;
    t.u[0] = a; t.u[1] = b; t.u[2] = c; t.u[3] = d;
    return t.v;
}

// ---------------- weight prepack (same layout as rounds 6/7) ----------------
__global__ void prepack_kernel(const float* __restrict__ Ws1, const float* __restrict__ bs1,
                               const float* __restrict__ Ws2, const float* __restrict__ Wr1,
                               const float* __restrict__ br1, const float* __restrict__ Wr2,
                               u16* __restrict__ ws)
{
    int idx = blockIdx.x * blockDim.x + threadIdx.x;
    if (idx >= 36864) return;
    int e = idx & 511, l = e >> 3, j = e & 7, hi = l >> 5, l31 = l & 31;
    float val = 0.0f;
    if (idx < 12288) {
        int blk = idx >> 9;
        if (blk < 18) {              // rot GEMM1
            int nt = blk / 3, kstep = blk % 3;
            int h = nt * 32 + l31;
            int k = kstep * 16 + 8 * hi + j;
            if (k < 32) {
                int t = k & 3, kk = k >> 2;
                int r_old = (t >> 1) * 16 + 2 * kk + (t & 1);
                val = Wr1[r_old * 192 + h];
            } else if (k == 32) val = br1[h];
        } else {                     // scalar GEMM1 (X cols 32..39 only)
            int h = (blk - 18) * 32 + l31;
            int k = 32 + 8 * hi + j;
            val = (k == 32) ? bs1[h] : ((k >= 33 && k <= 36) ? Ws1[(k - 33) * 192 + h] : 0.0f);
        }
    } else {
        int t = idx - 12288;
        int blk = t >> 9;
        int mlp = blk / 24, rem = blk % 24, ks = rem >> 1, nto = rem & 1;
        int k = 16 * ks + 8 * hi + j;
        int col = nto * 32 + l31;
        val = (mlp == 0 ? Wr2 : Ws2)[k * 64 + col];
    }
    ws[idx] = f2bf(val);
}

// ---------------- main fused kernel: 1 wave = 32 nodes, 4 waves/block ----------------
// Exact round-10 structure (147us verified): single coalesced rot_theta fetch via
// global_load_lds into XOR-swizzled per-wave LDS, featurization + epilogue rotation
// both read from LDS, non-temporal full-row output stores. r11's persistent-wave
// pipeline variant spilled to scratch (VGPR 64, +850MB scratch traffic, 608us) --
// this straight-line form is what the compiler schedules well.
__global__ __launch_bounds__(256, 4) void node_embed_mfma(
    const float* __restrict__ v, const float* __restrict__ force,
    const int* __restrict__ is_moving, const float* __restrict__ rot_theta,
    const float* __restrict__ br2, const float* __restrict__ bs2,
    const u16* __restrict__ wpack,
    float* __restrict__ out, int n)
{
    // per-wave union buffer (2560 B): phase 1 = Xs (32 x 40 u16),
    // phase 2 = Os (8 rows x 72 f32 = 2304 B). No cross-wave sharing -> no barriers.
    __shared__ alignas(16)  u16   Buf[4][1280];
    // per-wave rot_theta stash: 32 rows x 128 B, XOR-swizzled (off ^= (row&7)<<4)
    __shared__ alignas(128) float Rs[4][1024];

    const int lane = threadIdx.x & 63;
    const int w    = threadIdx.x >> 6;
    const int hi   = lane >> 5;
    const int l31  = lane & 31;
    const int waveBase = blockIdx.x * 128 + w * 32;

    u16*   Xs  = &Buf[w][0];
    float* Os  = reinterpret_cast<float*>(&Buf[w][0]);
    const char* RsB = reinterpret_cast<const char*>(&Rs[w][0]);

    // ---- cooperative rot_theta fetch: 4 x global_load_lds, 1KB contiguous each ----
    // LDS dest is linear (base + lane*16); the swizzle is applied to the SOURCE
    // address (involution: p ^= ((p>>7)&7)<<4), so swizzled reads decode correctly.
    {
        const char* gbase = reinterpret_cast<const char*>(rot_theta);
        const u32 inner = ((u32)(lane & 7) * 16u) ^ ((u32)(lane >> 3) << 4);
        #pragma unroll
        for (int i = 0; i < 4; ++i) {
            int node_i = waveBase + i * 8 + (lane >> 3);
            node_i = min(node_i, n - 1);
            const void* src = gbase + (size_t)node_i * 128 + inner;
            __builtin_amdgcn_global_load_lds(
                (const __attribute__((address_space(1))) u32*)src,
                (__attribute__((address_space(3))) u32*)(&Rs[w][i * 256]),
                16, 0, 0);
        }
    }

    // ---- per-node scalar inputs (2 lanes per node: hi=0 -> force, hi=1 -> v) ----
    const int node = waveBase + l31;
    const int ldn  = min(node, n - 1);

    const float2 p2 = *reinterpret_cast<const float2*>((hi ? v : force) + (size_t)ldn * 2);
    const float nrm = sqrtf(p2.x * p2.x + p2.y * p2.y);
    const float c = p2.x / nrm, s = p2.y / nrm;
    const int mov = is_moving[ldn];

    // wait for the LDS stash (and scalar loads) before consuming Rs
    asm volatile("s_waitcnt vmcnt(0)" ::: "memory");

    // ---- featurization recurrence reading R from Rs ----
    u16* xrow = Xs + l31 * 40;
    {
        float pc = c, ps = s;
        const u32 rowswz = (u32)(l31 & 7) << 4;
        #pragma unroll
        for (int k = 0; k < 8; ++k) {
            const u32 off = ((u32)(l31 * 128 + k * 16)) ^ rowswz;
            const float4 R = *reinterpret_cast<const float4*>(RsB + off);
            const float e0 = fmaf(R.x, pc, R.y * ps);
            const float e1 = fmaf(R.z, pc, R.w * ps);
            *reinterpret_cast<u32*>(xrow + 4 * k + 2 * hi) = cvt_pk_bf16(e0, e1);
            const float npc = pc * c - ps * s;
            ps = fmaf(ps, c, pc * s);
            pc = npc;
        }
    }
    // extras: cols 32..39 = [1.0, fn, vn, oh0, oh1, 0, 0, 0]
    {
        const u16 nb = f2bf(nrm);
        u32 pk1, pk2;
        if (hi == 0) { pk1 = 0x3F80u | ((u32)nb << 16);                    // (1.0, fn)
                       pk2 = (mov == 1) ? 0x3F80u : 0u; }                  // (oh1, 0)
        else         { pk1 = (u32)nb | ((mov == 0) ? 0x3F800000u : 0u);    // (vn, oh0)
                       pk2 = 0u; }                                         // (0, 0)
        *reinterpret_cast<u32*>(xrow + 32 + 2 * hi) = pk1;
        *reinterpret_cast<u32*>(xrow + 36 + 2 * hi) = pk2;
    }

    // ---- consume Xs into fragment registers (Xs dead afterwards) ----
    const bf16x8 xb0 = *reinterpret_cast<const bf16x8*>(&Xs[l31 * 40 + 8 * hi]);
    const bf16x8 xb1 = *reinterpret_cast<const bf16x8*>(&Xs[l31 * 40 + 16 + 8 * hi]);
    const bf16x8 xq4 = *reinterpret_cast<const bf16x8*>(&Xs[l31 * 40 + 32]); // hi=1 garbage x zero weights

    const u16* A1 = wpack;
    const u16* W2 = wpack + 12288;

    const int rowl = lane >> 4;   // epilogue: row within 4-row store group
    const int qd   = lane & 15;   // epilogue: float4 chunk within 64-col row

    // hoisted output biases
    const float b2r_a = br2[l31],      b2r_b = br2[32 + l31];
    const float b2s_a = bs2[l31],      b2s_b = bs2[32 + l31];

    #pragma unroll
    for (int mlp = 0; mlp < 2; ++mlp) {
        const float b2a = mlp ? b2s_a : b2r_a;
        const float b2b = mlp ? b2s_b : b2r_b;

        f32x16 acc0, acc1;
        #pragma unroll
        for (int r = 0; r < 16; ++r) { acc0[r] = b2a; acc1[r] = b2b; }

        #pragma unroll
        for (int a = 0; a < 6; ++a) {
            f32x16 d1;
            #pragma unroll
            for (int r = 0; r < 16; ++r) d1[r] = 0.0f;
            if (mlp == 0) {
                d1 = __builtin_amdgcn_mfma_f32_32x32x16_bf16(
                    *reinterpret_cast<const bf16x8*>(&A1[(a*3+0)*512 + lane*8]), xb0, d1, 0, 0, 0);
                d1 = __builtin_amdgcn_mfma_f32_32x32x16_bf16(
                    *reinterpret_cast<const bf16x8*>(&A1[(a*3+1)*512 + lane*8]), xb1, d1, 0, 0, 0);
                d1 = __builtin_amdgcn_mfma_f32_32x32x16_bf16(
                    *reinterpret_cast<const bf16x8*>(&A1[(a*3+2)*512 + lane*8]), xq4, d1, 0, 0, 0);
            } else {
                d1 = __builtin_amdgcn_mfma_f32_32x32x16_bf16(
                    *reinterpret_cast<const bf16x8*>(&A1[(18+a)*512 + lane*8]), xq4, d1, 0, 0, 0);
            }

            u32 q[8];
            #pragma unroll
            for (int m = 0; m < 8; ++m)
                q[m] = cvt_pk_bf16(fmaxf(d1[2*m], 0.0f), fmaxf(d1[2*m+1], 0.0f));

            #pragma unroll
            for (int b = 0; b < 2; ++b) {
                u32 p0 = q[4*b + 0], p2 = q[4*b + 2];
                u32 p1 = q[4*b + 1], p3 = q[4*b + 3];
                pl32_swap(p0, p2);
                pl32_swap(p1, p3);
                const bf16x8 af = frag_from(p0, p1, p2, p3);
                const int ks = 2*a + b;
                acc0 = __builtin_amdgcn_mfma_f32_32x32x16_bf16(
                    af, *reinterpret_cast<const bf16x8*>(&W2[(mlp*24 + ks*2 + 0)*512 + lane*8]),
                    acc0, 0, 0, 0);
                acc1 = __builtin_amdgcn_mfma_f32_32x32x16_bf16(
                    af, *reinterpret_cast<const bf16x8*>(&W2[(mlp*24 + ks*2 + 1)*512 + lane*8]),
                    acc1, 0, 0, 0);
            }
        }

        // ---- epilogue: stage 8 rows x 64 cols, rotate from Rs, nt full-row stores ----
        #pragma unroll
        for (int rq = 0; rq < 4; ++rq) {
            #pragma unroll
            for (int rr = 0; rr < 4; ++rr) {
                const int r = rq * 4 + rr;
                Os[(rr + 4*hi) * 72 + l31]      = acc0[r];
                Os[(rr + 4*hi) * 72 + 32 + l31] = acc1[r];
            }
            #pragma unroll
            for (int g = 0; g < 2; ++g) {
                const int row   = g * 4 + rowl;                      // 0..7
                const int srow  = rq * 8 + row;                      // 0..31 (Rs row)
                const int node0 = waveBase + srow;
                float4 o = *reinterpret_cast<const float4*>(&Os[row * 72 + 4 * qd]);
                if (mlp == 0) {
                    const u32 roff = ((u32)(srow * 128 + (qd & 3) * 32))
                                   ^ ((u32)(srow & 7) << 4);
                    const float4 Ra = *reinterpret_cast<const float4*>(RsB + roff);
                    const float4 Rc = *reinterpret_cast<const float4*>(RsB + (roff ^ 16u));
                    {
                        const float a0 = o.x, b0 = o.y;
                        o.x = fmaf(a0, Ra.x, b0 * Ra.z); o.y = fmaf(a0, Ra.y, b0 * Ra.w);
                    }
                    {
                        const float a0 = o.z, b0 = o.w;
                        o.z = fmaf(a0, Rc.x, b0 * Rc.z); o.w = fmaf(a0, Rc.y, b0 * Rc.w);
                    }
                }
                if (node0 < n) {
                    float* dst = out + (mlp ? (size_t)0 : (size_t)n * 64)
                                     + (size_t)node0 * 64 + 4 * qd;
                    f32x4v ov;
                    ov[0] = o.x; ov[1] = o.y; ov[2] = o.z; ov[3] = o.w;
                    __builtin_nontemporal_store(ov, reinterpret_cast<f32x4v*>(dst));
                }
            }
        }
    }
}

// ---------------- fallback (VALU) if ws too small ----------------
__global__ __launch_bounds__(256) void node_embed_valu(
    const float* __restrict__ v, const float* __restrict__ force,
    const int* __restrict__ is_moving, const float* __restrict__ rot_theta,
    const float* __restrict__ Ws1, const float* __restrict__ bs1,
    const float* __restrict__ Ws2, const float* __restrict__ bs2,
    const float* __restrict__ Wr1, const float* __restrict__ br1,
    const float* __restrict__ Wr2, const float* __restrict__ br2,
    float* __restrict__ out, int n)
{
    const int node = blockIdx.x * blockDim.x + threadIdx.x;
    if (node >= n) return;
    const float2 f2 = *reinterpret_cast<const float2*>(force + (size_t)node * 2);
    const float2 v2 = *reinterpret_cast<const float2*>(v     + (size_t)node * 2);
    const float fn = sqrtf(f2.x * f2.x + f2.y * f2.y);
    const float vn = sqrtf(v2.x * v2.x + v2.y * v2.y);
    const float cf = f2.x / fn, sf = f2.y / fn;
    const float cv = v2.x / vn, sv = v2.y / vn;
    const int mov = is_moving[node];
    float rotf[16], rotv[16];
    rotf[0] = cf; rotf[1] = sf; rotv[0] = cv; rotv[1] = sv;
    #pragma unroll
    for (int k = 1; k < 8; ++k) {
        rotf[2*k]   = rotf[2*k-2] * cf - rotf[2*k-1] * sf;
        rotf[2*k+1] = rotf[2*k-1] * cf + rotf[2*k-2] * sf;
        rotv[2*k]   = rotv[2*k-2] * cv - rotv[2*k-1] * sv;
        rotv[2*k+1] = rotv[2*k-1] * cv + rotv[2*k-2] * sv;
    }
    const float* Rb = rot_theta + (size_t)node * 32;
    float x_in[32];
    #pragma unroll
    for (int k = 0; k < 8; ++k) {
        const float4 R = *reinterpret_cast<const float4*>(Rb + k * 4);
        { const float a = rotf[2*k], b = rotf[2*k+1];
          x_in[2*k] = fmaf(R.x,a,R.y*b); x_in[2*k+1] = fmaf(R.z,a,R.w*b); }
        { const float a = rotv[2*k], b = rotv[2*k+1];
          x_in[16+2*k] = fmaf(R.x,a,R.y*b); x_in[16+2*k+1] = fmaf(R.z,a,R.w*b); }
    }
    float acc[64];
    #pragma unroll
    for (int j = 0; j < 64; ++j) acc[j] = br2[j];
    for (int h = 0; h < 192; h += 4) {
        float hid[4];
        #pragma unroll
        for (int u = 0; u < 4; ++u) {
            float t = br1[h+u];
            #pragma unroll
            for (int i = 0; i < 32; ++i) t = fmaf(x_in[i], Wr1[i*192+h+u], t);
            hid[u] = fmaxf(t, 0.0f);
        }
        #pragma unroll
        for (int j = 0; j < 64; ++j) {
            float t = acc[j];
            #pragma unroll
            for (int u = 0; u < 4; ++u) t = fmaf(hid[u], Wr2[(h+u)*64+j], t);
            acc[j] = t;
        }
    }
    #pragma unroll
    for (int k = 0; k < 8; ++k) {
        const float4 R = *reinterpret_cast<const float4*>(Rb + k * 4);
        #pragma unroll
        for (int j = 0; j < 4; ++j) {
            const int p = j*16 + 2*k;
            const float a = acc[p], b = acc[p+1];
            acc[p] = fmaf(a,R.x,b*R.z); acc[p+1] = fmaf(a,R.y,b*R.w);
        }
    }
    float* orow = out + (size_t)n * 64 + (size_t)node * 64;
    #pragma unroll
    for (int j = 0; j < 16; ++j)
        *reinterpret_cast<float4*>(orow + 4*j) =
            make_float4(acc[4*j], acc[4*j+1], acc[4*j+2], acc[4*j+3]);
    const float s0 = fn, s1 = vn, s2 = (mov==0)?1.f:0.f, s3 = (mov==1)?1.f:0.f;
    #pragma unroll
    for (int j = 0; j < 64; ++j) acc[j] = bs2[j];
    for (int h = 0; h < 192; h += 4) {
        float hid[4];
        #pragma unroll
        for (int u = 0; u < 4; ++u) {
            float t = bs1[h+u];
            t = fmaf(s0, Ws1[0*192+h+u], t); t = fmaf(s1, Ws1[1*192+h+u], t);
            t = fmaf(s2, Ws1[2*192+h+u], t); t = fmaf(s3, Ws1[3*192+h+u], t);
            hid[u] = fmaxf(t, 0.0f);
        }
        #pragma unroll
        for (int j = 0; j < 64; ++j) {
            float t = acc[j];
            #pragma unroll
            for (int u = 0; u < 4; ++u) t = fmaf(hid[u], Ws2[(h+u)*64+j], t);
            acc[j] = t;
        }
    }
    orow = out + (size_t)node * 64;
    #pragma unroll
    for (int j = 0; j < 16; ++j)
        *reinterpret_cast<float4*>(orow + 4*j) =
            make_float4(acc[4*j], acc[4*j+1], acc[4*j+2], acc[4*j+3]);
}

extern "C" void kernel_launch(void* const* d_in, const int* in_sizes, int n_in,
                              void* d_out, int out_size, void* d_ws, size_t ws_size,
                              hipStream_t stream) {
    const int n = in_sizes[0] / 2;
    if (ws_size >= 36864 * sizeof(u16)) {
        hipLaunchKernelGGL(prepack_kernel, dim3(144), dim3(256), 0, stream,
                           (const float*)d_in[4],   // Ws1
                           (const float*)d_in[5],   // bs1
                           (const float*)d_in[6],   // Ws2
                           (const float*)d_in[8],   // Wr1
                           (const float*)d_in[9],   // br1
                           (const float*)d_in[10],  // Wr2
                           (u16*)d_ws);
        hipLaunchKernelGGL(node_embed_mfma, dim3((n + 127) / 128), dim3(256), 0, stream,
                           (const float*)d_in[0], (const float*)d_in[1],
                           (const int*)d_in[2],   (const float*)d_in[3],
                           (const float*)d_in[11],  // br2
                           (const float*)d_in[7],   // bs2
                           (const u16*)d_ws, (float*)d_out, n);
    } else {
        hipLaunchKernelGGL(node_embed_valu, dim3((n + 255) / 256), dim3(256), 0, stream,
                           (const float*)d_in[0], (const float*)d_in[1],
                           (const int*)d_in[2],   (const float*)d_in[3],
                           (const float*)d_in[4], (const float*)d_in[5],
                           (const float*)d_in[6], (const float*)d_in[7],
                           (const float*)d_in[8], (const float*)d_in[9],
                           (const float*)d_in[10],(const float*)d_in[11],
                           (float*)d_out, n);
    }
}